// Round 14
// baseline (97.531 us; speedup 1.0000x reference)
//
#include <hip/hip_runtime.h>
#include <hip/hip_fp16.h>
#include <stdint.h>

#define HH 2048
#define WW 2048
#define NS 1024
#define NIMG 64
#define ESZ 256
#define NCOL 69      // x, y, h, w, d, c[64]
#define EPS_T 0.010f // transmittance cutoff; truncation error <= EPS_T

#define NBLK_PREP 4
#define TEX_PER_BLK 4096
#define NBLK_IL (NIMG * 65536 / TEX_PER_BLK)   // 1024 interleave blocks

typedef float    f32x4 __attribute__((ext_vector_type(4)));
typedef uint32_t u32x4 __attribute__((ext_vector_type(4)));

// ---------------------------------------------------------------------------
// Fused kernel. Blocks [0,4): decode+rank 256 samples each (hidden under the
// grid). Blocks [4, 4+1024): planar f32 -> RGBA8 via wave-specialized reads:
// wave w reads ONLY channel w (contiguous 4KB/round per wave), quantizes to
// bytes in LDS, then a byte-transpose emits u32x4 RGBA8 stores. This removes
// the 4-interleaved-strided-streams-per-wave pattern of all prior variants.
// ---------------------------------------------------------------------------
__global__ __launch_bounds__(256) void prep_interleave_kernel(const float* __restrict__ data,
                                                              const float* __restrict__ images,
                                                              uint32_t* __restrict__ chuf,
                                                              uint32_t* __restrict__ pos) {
    __shared__ uint32_t Wbuf[1024];   // 4KB; prep reuses as depth cache
    const int tid = threadIdx.x;

    if (blockIdx.x >= NBLK_PREP) {
        const size_t gbase = (size_t)(blockIdx.x - NBLK_PREP) * TEX_PER_BLK;
        const size_t img   = gbase >> 16;
        const float* ibase = images + img * (size_t)(4 * 65536);
        const int wv = tid >> 6;          // wave -> channel
        const int l  = tid & 63;

        #pragma unroll
        for (int r = 0; r < 4; ++r) {
            const size_t sb = (gbase & 65535) + (size_t)r * 1024;   // round base (texels)
            // phase A: wave wv streams channel wv, 4KB contiguous
            #pragma unroll
            for (int k = 0; k < 4; ++k) {
                const f32x4 v = *(const f32x4*)(ibase + (size_t)wv * 65536 + sb + k * 256 + l * 4);
                const uint32_t pw = ((uint32_t)(v.x * 255.0f + 0.5f))
                                  | ((uint32_t)(v.y * 255.0f + 0.5f) << 8)
                                  | ((uint32_t)(v.z * 255.0f + 0.5f) << 16)
                                  | ((uint32_t)(v.w * 255.0f + 0.5f) << 24);
                Wbuf[wv * 256 + k * 64 + l] = pw;   // 4B stride -> conflict-free
            }
            __syncthreads();
            // phase B: byte-transpose -> 4 RGBA8 words -> u32x4 store
            const uint32_t c0 = Wbuf[tid];
            const uint32_t c1 = Wbuf[256 + tid];
            const uint32_t c2 = Wbuf[512 + tid];
            const uint32_t c3 = Wbuf[768 + tid];
            u32x4 o;
            o.x = ( c0        & 0xFFu) | (( c1        & 0xFFu) << 8) | (( c2        & 0xFFu) << 16) | (( c3        & 0xFFu) << 24);
            o.y = ((c0 >>  8) & 0xFFu) | (((c1 >>  8) & 0xFFu) << 8) | (((c2 >>  8) & 0xFFu) << 16) | (((c3 >>  8) & 0xFFu) << 24);
            o.z = ((c0 >> 16) & 0xFFu) | (((c1 >> 16) & 0xFFu) << 8) | (((c2 >> 16) & 0xFFu) << 16) | (((c3 >> 16) & 0xFFu) << 24);
            o.w = ( c0 >> 24         ) | (( c1 >> 24         ) << 8) | (( c2 >> 24         ) << 16) | (( c3 >> 24         ) << 24);
            *(u32x4*)(chuf + gbase + (size_t)r * 1024 + (size_t)tid * 4) = o;
            __syncthreads();   // protect Wbuf for next round
        }
        return;
    }

    // ---- prep: this block ranks samples [blockIdx*256, +256) ----
    float* ds = (float*)Wbuf;
    #pragma unroll
    for (int k = 0; k < 4; ++k) {
        const int s = tid + 256 * k;
        ds[s] = data[s * NCOL + 4];
    }
    __syncthreads();

    const int s = (int)blockIdx.x * 256 + tid;
    const float* row = data + s * NCOL;
    const float d = ds[s];
    const int x = (int)rintf(row[0] * (float)HH);   // round-half-even == jnp.round
    const int y = (int)rintf(row[1] * (float)WW);
    const int h = (int)rintf(row[2] * (float)HH);
    const int w = (int)rintf(row[3] * (float)WW);
    const int x1 = x - h / 2;
    const int y1 = y - w / 2;

    float best = row[5];
    int bi = 0;
    #pragma unroll 8
    for (int j = 1; j < NIMG; ++j) {
        float v = row[5 + j];
        if (v > best) { best = v; bi = j; }
    }

    int rank = 0;
    for (int j4 = 0; j4 < NS / 4; ++j4) {
        const float4 dj = *(const float4*)&ds[j4 * 4];   // broadcast b128 read
        const int j0 = j4 * 4;
        rank += (int)((dj.x < d) | ((dj.x == d) & (j0     < s)));
        rank += (int)((dj.y < d) | ((dj.y == d) & (j0 + 1 < s)));
        rank += (int)((dj.z < d) | ((dj.z == d) & (j0 + 2 < s)));
        rank += (int)((dj.w < d) | ((dj.w == d) & (j0 + 3 < s)));
    }
    pos[rank] = ((uint32_t)x1 << 17) | ((uint32_t)y1 << 6) | (uint32_t)bi;
}

// ---------------------------------------------------------------------------
// Composite: one block per 32x32 tile, 4 px/thread. Front-to-back
// transmittance, RGBA8 gathers, TWO list entries per iteration (stale
// predicate, applied in order) -> 8 outstanding gathers per thread.
// ---------------------------------------------------------------------------
__global__ __launch_bounds__(256) void comp_half_kernel(const uint32_t* __restrict__ chuf,
                                                        const uint32_t* __restrict__ pos,
                                                        float* __restrict__ out) {
    __shared__ uint32_t list[NS];
    __shared__ int wcnt[4];

    const int tid  = threadIdx.x;
    const int lane = tid & 63;
    const int wv   = tid >> 6;

    const int tileR = blockIdx.x >> 6;    // 64x64 tiles of 32x32
    const int tileC = blockIdx.x & 63;
    const int r0 = tileR * 32;
    const int c0 = tileC * 32;

    // ---- binning: sprites whose bbox intersects this tile (depth order) ----
    int run = 0;
    for (int base = 0; base < NS; base += 256) {
        const uint32_t p = pos[base + tid];
        const int x1 = (int)(p >> 17);
        const int y1 = (int)((p >> 6) & 0x7FF);
        const bool hit = (x1 >= r0 - (ESZ - 1)) && (x1 <= r0 + 31) &&
                         (y1 >= c0 - (ESZ - 1)) && (y1 <= c0 + 31);
        const uint64_t m = __ballot(hit);
        if (lane == 0) wcnt[wv] = __popcll(m);
        __syncthreads();
        int off = run;
        for (int w2 = 0; w2 < wv; ++w2) off += wcnt[w2];
        if (hit) {
            const int slot = __popcll(m & ((1ull << lane) - 1ull));
            list[off + slot] = p;
        }
        run += wcnt[0] + wcnt[1] + wcnt[2] + wcnt[3];
        __syncthreads();
    }
    const int n = run;

    // ---- per-thread: 4 pixels (16x16 quadrants of the 32x32 tile) ----
    const int px0 = c0 + (tid & 15);
    const int py0 = r0 + (tid >> 4);

    float cr[4], cg[4], cb[4], T[4];
    #pragma unroll
    for (int q = 0; q < 4; ++q) { cr[q] = 0.0f; cg[q] = 0.0f; cb[q] = 0.0f; T[q] = 1.0f; }

    // front-to-back walk (descending index), two entries per iteration
    int s = n - 1;
    while (s >= 1) {
        const uint32_t pA = list[s];
        const uint32_t pB = list[s - 1];
        const int xA = (int)(pA >> 17), yA = (int)((pA >> 6) & 0x7FF);
        const int xB = (int)(pB >> 17), yB = (int)((pB >> 6) & 0x7FF);
        const size_t ibA = ((size_t)(pA & 0x3F)) << 16;
        const size_t ibB = ((size_t)(pB & 0x3F)) << 16;
        const int ryA = py0 - xA, rxA = px0 - yA;
        const int ryB = py0 - xB, rxB = px0 - yB;

        uint32_t cvA[4], cvB[4];
        bool okA[4], okB[4];
        #pragma unroll
        for (int q = 0; q < 4; ++q) {
            const int dy = (q >> 1) << 4, dx = (q & 1) << 4;
            const int syA = ryA + dy, sxA = rxA + dx;
            const int syB = ryB + dy, sxB = rxB + dx;
            const bool alive = T[q] > EPS_T;
            okA[q] = alive & ((unsigned)syA < ESZ) & ((unsigned)sxA < ESZ);
            okB[q] = alive & ((unsigned)syB < ESZ) & ((unsigned)sxB < ESZ);
            if (okA[q]) cvA[q] = chuf[ibA + (size_t)((syA << 8) + sxA)];
            if (okB[q]) cvB[q] = chuf[ibB + (size_t)((syB << 8) + sxB)];
        }
        #pragma unroll
        for (int q = 0; q < 4; ++q) {
            if (okA[q]) {
                const uint32_t cv = cvA[q];
                const float a = (float)(cv >> 24) * (1.0f / 255.0f);
                const float w = T[q] * a;
                cr[q] += w * (float)(cv & 0xFFu);
                cg[q] += w * (float)((cv >> 8) & 0xFFu);
                cb[q] += w * (float)((cv >> 16) & 0xFFu);
                T[q] *= (1.0f - a);
            }
            if (okB[q] & (T[q] > EPS_T)) {
                const uint32_t cv = cvB[q];
                const float a = (float)(cv >> 24) * (1.0f / 255.0f);
                const float w = T[q] * a;
                cr[q] += w * (float)(cv & 0xFFu);
                cg[q] += w * (float)((cv >> 8) & 0xFFu);
                cb[q] += w * (float)((cv >> 16) & 0xFFu);
                T[q] *= (1.0f - a);
            }
        }
        s -= 2;
        const bool alive = (T[0] > EPS_T) | (T[1] > EPS_T) | (T[2] > EPS_T) | (T[3] > EPS_T);
        if (!__any(alive)) break;
    }
    if (s == 0) {   // back-most leftover entry
        const uint32_t p = list[0];
        const int x1 = (int)(p >> 17);
        const int y1 = (int)((p >> 6) & 0x7FF);
        const size_t ib = ((size_t)(p & 0x3F)) << 16;
        const int ry = py0 - x1;
        const int rx = px0 - y1;
        #pragma unroll
        for (int q = 0; q < 4; ++q) {
            if (T[q] > EPS_T) {
                const int sy = ry + ((q >> 1) << 4);
                const int sx = rx + ((q & 1) << 4);
                if ((unsigned)sy < ESZ && (unsigned)sx < ESZ) {
                    const uint32_t cv = chuf[ib + (size_t)((sy << 8) + sx)];
                    const float a = (float)(cv >> 24) * (1.0f / 255.0f);
                    const float w = T[q] * a;
                    cr[q] += w * (float)(cv & 0xFFu);
                    cg[q] += w * (float)((cv >> 8) & 0xFFu);
                    cb[q] += w * (float)((cv >> 16) & 0xFFu);
                    T[q] *= (1.0f - a);
                }
            }
        }
    }

    #pragma unroll
    for (int q = 0; q < 4; ++q) {
        const int py = py0 + ((q >> 1) << 4);
        const int px = px0 + ((q & 1) << 4);
        const size_t o = (size_t)py * WW + px;
        const float sc = 1.0f / 255.0f;
        __builtin_nontemporal_store(cr[q] * sc + T[q], out + o);
        __builtin_nontemporal_store(cg[q] * sc + T[q], out + (size_t)HH * WW + o);
        __builtin_nontemporal_store(cb[q] * sc + T[q], out + (size_t)2 * HH * WW + o);
        __builtin_nontemporal_store(1.0f,              out + (size_t)3 * HH * WW + o);
    }
}

// ---------------------------------------------------------------------------
// Fallback (fp32 planar, back-to-front "over") — only if ws too small.
// ---------------------------------------------------------------------------
__global__ __launch_bounds__(1024) void prep_kernel(const float* __restrict__ data,
                                                    uint32_t* __restrict__ pos) {
    __shared__ float ds[NS];
    const int t = threadIdx.x;
    const float* row = data + t * NCOL;
    const float d = row[4];
    const int x = (int)rintf(row[0] * (float)HH);
    const int y = (int)rintf(row[1] * (float)WW);
    const int h = (int)rintf(row[2] * (float)HH);
    const int w = (int)rintf(row[3] * (float)WW);
    const int x1 = x - h / 2;
    const int y1 = y - w / 2;
    float best = row[5];
    int bi = 0;
    for (int j = 1; j < NIMG; ++j) {
        float v = row[5 + j];
        if (v > best) { best = v; bi = j; }
    }
    ds[t] = d;
    __syncthreads();
    int rank = 0;
    for (int j = 0; j < NS; ++j) {
        float dj = ds[j];
        rank += (int)((dj < d) | ((dj == d) & (j < t)));
    }
    pos[rank] = ((uint32_t)x1 << 17) | ((uint32_t)y1 << 6) | (uint32_t)bi;
}

__global__ __launch_bounds__(256) void comp_kernel(const float* __restrict__ images,
                                                   const uint32_t* __restrict__ pos,
                                                   float* __restrict__ out) {
    __shared__ uint32_t list[NS];
    __shared__ int wcnt[4];
    const int tid  = threadIdx.x;
    const int lane = tid & 63;
    const int wv   = tid >> 6;
    const int tileR = blockIdx.x >> 7;
    const int tileC = blockIdx.x & 127;
    const int r0 = tileR * 16;
    const int c0 = tileC * 16;
    int run = 0;
    for (int base = 0; base < NS; base += 256) {
        const uint32_t p = pos[base + tid];
        const int x1 = (int)(p >> 17);
        const int y1 = (int)((p >> 6) & 0x7FF);
        const bool hit = (x1 >= r0 - (ESZ - 1)) && (x1 <= r0 + 15) &&
                         (y1 >= c0 - (ESZ - 1)) && (y1 <= c0 + 15);
        const uint64_t m = __ballot(hit);
        if (lane == 0) wcnt[wv] = __popcll(m);
        __syncthreads();
        int off = run;
        for (int w2 = 0; w2 < wv; ++w2) off += wcnt[w2];
        if (hit) {
            const int slot = __popcll(m & ((1ull << lane) - 1ull));
            list[off + slot] = p;
        }
        run += wcnt[0] + wcnt[1] + wcnt[2] + wcnt[3];
        __syncthreads();
    }
    const int n = run;
    const int px = c0 + (tid & 15);
    const int py = r0 + (tid >> 4);
    float r = 1.0f, g = 1.0f, b = 1.0f;
    for (int s = 0; s < n; ++s) {
        const uint32_t p = list[s];
        const int x1 = (int)(p >> 17);
        const int y1 = (int)((p >> 6) & 0x7FF);
        const int ii = (int)(p & 0x3F);
        const int sy = py - x1;
        const int sx = px - y1;
        if ((unsigned)sy < ESZ && (unsigned)sx < ESZ) {
            const float* sp = images + (size_t)ii * (4 * ESZ * ESZ) + sy * ESZ + sx;
            const float sr = sp[0];
            const float sg = sp[ESZ * ESZ];
            const float sb = sp[2 * ESZ * ESZ];
            const float a  = sp[3 * ESZ * ESZ];
            const float ia = 1.0f - a;
            r = r * ia + sr * a;
            g = g * ia + sg * a;
            b = b * ia + sb * a;
        }
    }
    const size_t o = (size_t)py * WW + px;
    out[o]                        = r;
    out[(size_t)HH * WW     + o]  = g;
    out[(size_t)2 * HH * WW + o]  = b;
    out[(size_t)3 * HH * WW + o]  = 1.0f;
}

extern "C" void kernel_launch(void* const* d_in, const int* in_sizes, int n_in,
                              void* d_out, int out_size, void* d_ws, size_t ws_size,
                              hipStream_t stream) {
    const float* data   = (const float*)d_in[0];
    const float* images = (const float*)d_in[1];
    float* out          = (float*)d_out;

    uint32_t* pos = (uint32_t*)d_ws;                                   // 4 KB
    const size_t chuf_off = 4096;
    const size_t chuf_bytes = (size_t)NIMG * 65536 * 4;                // 16.8 MB RGBA8

    if (ws_size >= chuf_off + chuf_bytes) {
        uint32_t* chuf = (uint32_t*)((char*)d_ws + chuf_off);
        prep_interleave_kernel<<<NBLK_PREP + NBLK_IL, 256, 0, stream>>>(data, images, chuf, pos);
        comp_half_kernel<<<(HH / 32) * (WW / 32), 256, 0, stream>>>(chuf, pos, out);
    } else {
        prep_kernel<<<1, NS, 0, stream>>>(data, pos);
        comp_kernel<<<(HH / 16) * (WW / 16), 256, 0, stream>>>(images, pos, out);
    }
}

// Round 15
// 86.877 us; speedup vs baseline: 1.1226x; 1.1226x over previous
//
#include <hip/hip_runtime.h>
#include <hip/hip_fp16.h>
#include <stdint.h>

#define HH 2048
#define WW 2048
#define NS 1024
#define NIMG 64
#define ESZ 256
#define NCOL 69      // x, y, h, w, d, c[64]
#define EPS_T 0.010f // transmittance cutoff; truncation error <= EPS_T

#define NBLK_PREP 4
#define NBLK_IL (NIMG * 65536 / 256)     // 16384 interleave blocks, 1 px/thread

typedef float    f32x4 __attribute__((ext_vector_type(4)));
typedef uint32_t u32x4 __attribute__((ext_vector_type(4)));

__device__ __forceinline__ uint32_t pack_rgba8(float r, float g, float b, float a) {
    const uint32_t ri = (uint32_t)(r * 255.0f + 0.5f);
    const uint32_t gi = (uint32_t)(g * 255.0f + 0.5f);
    const uint32_t bi = (uint32_t)(b * 255.0f + 0.5f);
    const uint32_t ai = (uint32_t)(a * 255.0f + 0.5f);
    return ri | (gi << 8) | (bi << 16) | (ai << 24);
}

// ---------------------------------------------------------------------------
// Fused kernel (R13 measured-best): blocks [0,4) prep; blocks [4,4+16384)
// planar f32 -> RGBA8 at 1 px/thread.
// ---------------------------------------------------------------------------
__global__ __launch_bounds__(256) void prep_interleave_kernel(const float* __restrict__ data,
                                                              const float* __restrict__ images,
                                                              uint32_t* __restrict__ chuf,
                                                              uint32_t* __restrict__ pos) {
    const int tid = threadIdx.x;

    if (blockIdx.x >= NBLK_PREP) {
        const size_t g = (size_t)(blockIdx.x - NBLK_PREP) * 256 + tid;
        const size_t img = g >> 16;
        const size_t p   = g & 65535;
        const float* base = images + img * (size_t)(4 * 65536) + p;
        const float r = base[0];
        const float gg = base[65536];
        const float b = base[2 * 65536];
        const float a = base[3 * 65536];
        chuf[g] = pack_rgba8(r, gg, b, a);
        return;
    }

    // ---- prep: this block ranks samples [blockIdx*256, +256) ----
    __shared__ float ds[NS];
    #pragma unroll
    for (int k = 0; k < 4; ++k) {
        const int s = tid + 256 * k;
        ds[s] = data[s * NCOL + 4];
    }
    __syncthreads();

    const int s = (int)blockIdx.x * 256 + tid;
    const float* row = data + s * NCOL;
    const float d = ds[s];
    const int x = (int)rintf(row[0] * (float)HH);   // round-half-even == jnp.round
    const int y = (int)rintf(row[1] * (float)WW);
    const int h = (int)rintf(row[2] * (float)HH);
    const int w = (int)rintf(row[3] * (float)WW);
    const int x1 = x - h / 2;
    const int y1 = y - w / 2;

    float best = row[5];
    int bi = 0;
    #pragma unroll 8
    for (int j = 1; j < NIMG; ++j) {
        float v = row[5 + j];
        if (v > best) { best = v; bi = j; }
    }

    int rank = 0;
    for (int j4 = 0; j4 < NS / 4; ++j4) {
        const float4 dj = *(const float4*)&ds[j4 * 4];   // broadcast b128 read
        const int j0 = j4 * 4;
        rank += (int)((dj.x < d) | ((dj.x == d) & (j0     < s)));
        rank += (int)((dj.y < d) | ((dj.y == d) & (j0 + 1 < s)));
        rank += (int)((dj.z < d) | ((dj.z == d) & (j0 + 2 < s)));
        rank += (int)((dj.w < d) | ((dj.w == d) & (j0 + 3 < s)));
    }
    pos[rank] = ((uint32_t)x1 << 17) | ((uint32_t)y1 << 6) | (uint32_t)bi;
}

// ---------------------------------------------------------------------------
// Composite: one block per 32x32 tile, 4 px/thread, pairwise-pipelined
// front-to-back RGBA8. XCD-aware tile swizzle: blockIdx round-robins XCDs, so
// map bid -> (bid&7)*512 + (bid>>3): each XCD gets a contiguous 256-px-tall
// band; a 256-tall sprite spans <=2 bands -> each chuf line fetched by <=2
// XCD L2s instead of ~8 (measured 6.4x fetch amplification without this).
// ---------------------------------------------------------------------------
__global__ __launch_bounds__(256) void comp_half_kernel(const uint32_t* __restrict__ chuf,
                                                        const uint32_t* __restrict__ pos,
                                                        float* __restrict__ out) {
    __shared__ uint32_t list[NS];
    __shared__ int wcnt[4];

    const int tid  = threadIdx.x;
    const int lane = tid & 63;
    const int wv   = tid >> 6;

    const int swz = ((int)(blockIdx.x & 7) << 9) | ((int)blockIdx.x >> 3);  // bijective on [0,4096)
    const int tileR = swz >> 6;    // 64x64 tiles of 32x32
    const int tileC = swz & 63;
    const int r0 = tileR * 32;
    const int c0 = tileC * 32;

    // ---- binning: sprites whose bbox intersects this tile (depth order) ----
    int run = 0;
    for (int base = 0; base < NS; base += 256) {
        const uint32_t p = pos[base + tid];
        const int x1 = (int)(p >> 17);
        const int y1 = (int)((p >> 6) & 0x7FF);
        const bool hit = (x1 >= r0 - (ESZ - 1)) && (x1 <= r0 + 31) &&
                         (y1 >= c0 - (ESZ - 1)) && (y1 <= c0 + 31);
        const uint64_t m = __ballot(hit);
        if (lane == 0) wcnt[wv] = __popcll(m);
        __syncthreads();
        int off = run;
        for (int w2 = 0; w2 < wv; ++w2) off += wcnt[w2];
        if (hit) {
            const int slot = __popcll(m & ((1ull << lane) - 1ull));
            list[off + slot] = p;
        }
        run += wcnt[0] + wcnt[1] + wcnt[2] + wcnt[3];
        __syncthreads();
    }
    const int n = run;

    // ---- per-thread: 4 pixels (16x16 quadrants of the 32x32 tile) ----
    const int px0 = c0 + (tid & 15);
    const int py0 = r0 + (tid >> 4);

    float cr[4], cg[4], cb[4], T[4];
    #pragma unroll
    for (int q = 0; q < 4; ++q) { cr[q] = 0.0f; cg[q] = 0.0f; cb[q] = 0.0f; T[q] = 1.0f; }

    // front-to-back walk (descending index), two entries per iteration
    int s = n - 1;
    while (s >= 1) {
        const uint32_t pA = list[s];
        const uint32_t pB = list[s - 1];
        const int xA = (int)(pA >> 17), yA = (int)((pA >> 6) & 0x7FF);
        const int xB = (int)(pB >> 17), yB = (int)((pB >> 6) & 0x7FF);
        const size_t ibA = ((size_t)(pA & 0x3F)) << 16;
        const size_t ibB = ((size_t)(pB & 0x3F)) << 16;
        const int ryA = py0 - xA, rxA = px0 - yA;
        const int ryB = py0 - xB, rxB = px0 - yB;

        uint32_t cvA[4], cvB[4];
        bool okA[4], okB[4];
        #pragma unroll
        for (int q = 0; q < 4; ++q) {
            const int dy = (q >> 1) << 4, dx = (q & 1) << 4;
            const int syA = ryA + dy, sxA = rxA + dx;
            const int syB = ryB + dy, sxB = rxB + dx;
            const bool alive = T[q] > EPS_T;
            okA[q] = alive & ((unsigned)syA < ESZ) & ((unsigned)sxA < ESZ);
            okB[q] = alive & ((unsigned)syB < ESZ) & ((unsigned)sxB < ESZ);
            if (okA[q]) cvA[q] = chuf[ibA + (size_t)((syA << 8) + sxA)];
            if (okB[q]) cvB[q] = chuf[ibB + (size_t)((syB << 8) + sxB)];
        }
        #pragma unroll
        for (int q = 0; q < 4; ++q) {
            if (okA[q]) {
                const uint32_t cv = cvA[q];
                const float a = (float)(cv >> 24) * (1.0f / 255.0f);
                const float w = T[q] * a;
                cr[q] += w * (float)(cv & 0xFFu);
                cg[q] += w * (float)((cv >> 8) & 0xFFu);
                cb[q] += w * (float)((cv >> 16) & 0xFFu);
                T[q] *= (1.0f - a);
            }
            if (okB[q] & (T[q] > EPS_T)) {
                const uint32_t cv = cvB[q];
                const float a = (float)(cv >> 24) * (1.0f / 255.0f);
                const float w = T[q] * a;
                cr[q] += w * (float)(cv & 0xFFu);
                cg[q] += w * (float)((cv >> 8) & 0xFFu);
                cb[q] += w * (float)((cv >> 16) & 0xFFu);
                T[q] *= (1.0f - a);
            }
        }
        s -= 2;
        const bool alive = (T[0] > EPS_T) | (T[1] > EPS_T) | (T[2] > EPS_T) | (T[3] > EPS_T);
        if (!__any(alive)) break;
    }
    if (s == 0) {   // back-most leftover entry
        const uint32_t p = list[0];
        const int x1 = (int)(p >> 17);
        const int y1 = (int)((p >> 6) & 0x7FF);
        const size_t ib = ((size_t)(p & 0x3F)) << 16;
        const int ry = py0 - x1;
        const int rx = px0 - y1;
        #pragma unroll
        for (int q = 0; q < 4; ++q) {
            if (T[q] > EPS_T) {
                const int sy = ry + ((q >> 1) << 4);
                const int sx = rx + ((q & 1) << 4);
                if ((unsigned)sy < ESZ && (unsigned)sx < ESZ) {
                    const uint32_t cv = chuf[ib + (size_t)((sy << 8) + sx)];
                    const float a = (float)(cv >> 24) * (1.0f / 255.0f);
                    const float w = T[q] * a;
                    cr[q] += w * (float)(cv & 0xFFu);
                    cg[q] += w * (float)((cv >> 8) & 0xFFu);
                    cb[q] += w * (float)((cv >> 16) & 0xFFu);
                    T[q] *= (1.0f - a);
                }
            }
        }
    }

    #pragma unroll
    for (int q = 0; q < 4; ++q) {
        const int py = py0 + ((q >> 1) << 4);
        const int px = px0 + ((q & 1) << 4);
        const size_t o = (size_t)py * WW + px;
        const float sc = 1.0f / 255.0f;
        __builtin_nontemporal_store(cr[q] * sc + T[q], out + o);
        __builtin_nontemporal_store(cg[q] * sc + T[q], out + (size_t)HH * WW + o);
        __builtin_nontemporal_store(cb[q] * sc + T[q], out + (size_t)2 * HH * WW + o);
        __builtin_nontemporal_store(1.0f,              out + (size_t)3 * HH * WW + o);
    }
}

// ---------------------------------------------------------------------------
// Fallback (fp32 planar, back-to-front "over") — only if ws too small.
// ---------------------------------------------------------------------------
__global__ __launch_bounds__(1024) void prep_kernel(const float* __restrict__ data,
                                                    uint32_t* __restrict__ pos) {
    __shared__ float ds[NS];
    const int t = threadIdx.x;
    const float* row = data + t * NCOL;
    const float d = row[4];
    const int x = (int)rintf(row[0] * (float)HH);
    const int y = (int)rintf(row[1] * (float)WW);
    const int h = (int)rintf(row[2] * (float)HH);
    const int w = (int)rintf(row[3] * (float)WW);
    const int x1 = x - h / 2;
    const int y1 = y - w / 2;
    float best = row[5];
    int bi = 0;
    for (int j = 1; j < NIMG; ++j) {
        float v = row[5 + j];
        if (v > best) { best = v; bi = j; }
    }
    ds[t] = d;
    __syncthreads();
    int rank = 0;
    for (int j = 0; j < NS; ++j) {
        float dj = ds[j];
        rank += (int)((dj < d) | ((dj == d) & (j < t)));
    }
    pos[rank] = ((uint32_t)x1 << 17) | ((uint32_t)y1 << 6) | (uint32_t)bi;
}

__global__ __launch_bounds__(256) void comp_kernel(const float* __restrict__ images,
                                                   const uint32_t* __restrict__ pos,
                                                   float* __restrict__ out) {
    __shared__ uint32_t list[NS];
    __shared__ int wcnt[4];
    const int tid  = threadIdx.x;
    const int lane = tid & 63;
    const int wv   = tid >> 6;
    const int tileR = blockIdx.x >> 7;
    const int tileC = blockIdx.x & 127;
    const int r0 = tileR * 16;
    const int c0 = tileC * 16;
    int run = 0;
    for (int base = 0; base < NS; base += 256) {
        const uint32_t p = pos[base + tid];
        const int x1 = (int)(p >> 17);
        const int y1 = (int)((p >> 6) & 0x7FF);
        const bool hit = (x1 >= r0 - (ESZ - 1)) && (x1 <= r0 + 15) &&
                         (y1 >= c0 - (ESZ - 1)) && (y1 <= c0 + 15);
        const uint64_t m = __ballot(hit);
        if (lane == 0) wcnt[wv] = __popcll(m);
        __syncthreads();
        int off = run;
        for (int w2 = 0; w2 < wv; ++w2) off += wcnt[w2];
        if (hit) {
            const int slot = __popcll(m & ((1ull << lane) - 1ull));
            list[off + slot] = p;
        }
        run += wcnt[0] + wcnt[1] + wcnt[2] + wcnt[3];
        __syncthreads();
    }
    const int n = run;
    const int px = c0 + (tid & 15);
    const int py = r0 + (tid >> 4);
    float r = 1.0f, g = 1.0f, b = 1.0f;
    for (int s = 0; s < n; ++s) {
        const uint32_t p = list[s];
        const int x1 = (int)(p >> 17);
        const int y1 = (int)((p >> 6) & 0x7FF);
        const int ii = (int)(p & 0x3F);
        const int sy = py - x1;
        const int sx = px - y1;
        if ((unsigned)sy < ESZ && (unsigned)sx < ESZ) {
            const float* sp = images + (size_t)ii * (4 * ESZ * ESZ) + sy * ESZ + sx;
            const float sr = sp[0];
            const float sg = sp[ESZ * ESZ];
            const float sb = sp[2 * ESZ * ESZ];
            const float a  = sp[3 * ESZ * ESZ];
            const float ia = 1.0f - a;
            r = r * ia + sr * a;
            g = g * ia + sg * a;
            b = b * ia + sb * a;
        }
    }
    const size_t o = (size_t)py * WW + px;
    out[o]                        = r;
    out[(size_t)HH * WW     + o]  = g;
    out[(size_t)2 * HH * WW + o]  = b;
    out[(size_t)3 * HH * WW + o]  = 1.0f;
}

extern "C" void kernel_launch(void* const* d_in, const int* in_sizes, int n_in,
                              void* d_out, int out_size, void* d_ws, size_t ws_size,
                              hipStream_t stream) {
    const float* data   = (const float*)d_in[0];
    const float* images = (const float*)d_in[1];
    float* out          = (float*)d_out;

    uint32_t* pos = (uint32_t*)d_ws;                                   // 4 KB
    const size_t chuf_off = 4096;
    const size_t chuf_bytes = (size_t)NIMG * 65536 * 4;                // 16.8 MB RGBA8

    if (ws_size >= chuf_off + chuf_bytes) {
        uint32_t* chuf = (uint32_t*)((char*)d_ws + chuf_off);
        prep_interleave_kernel<<<NBLK_PREP + NBLK_IL, 256, 0, stream>>>(data, images, chuf, pos);
        comp_half_kernel<<<(HH / 32) * (WW / 32), 256, 0, stream>>>(chuf, pos, out);
    } else {
        prep_kernel<<<1, NS, 0, stream>>>(data, pos);
        comp_kernel<<<(HH / 16) * (WW / 16), 256, 0, stream>>>(images, pos, out);
    }
}